// Round 19
// baseline (196.664 us; speedup 1.0000x reference)
//
#include <hip/hip_runtime.h>
#include <hip/hip_bf16.h>
#include <hip/hip_fp16.h>

// 2D DCT-II via LEVEL-2 folded f16 MFMA GEMMs.
// R19: merged GEMM switched from 4-buffer/128KB (1 block/CU, Occ 15.6%,
// MfmaUtil 26%) to R5's 2-buffer/64KB ring WITHOUT launch_bounds min-waves
// (R5's regression was solely __launch_bounds__(512,4) forcing 64-VGPR acc
// spill; natural 92 VGPR x 4 waves/SIMD fits 2 blocks/CU). Co-resident block
// hides the per-tile vmcnt(0) drain (m114). Sync ledger = R5 (HW-validated):
// ph1 {reads q0 + stage both t+1 into buf[(t+1)&1]}, barrier, MFMA;
// ph2 {reads q1, lgkmcnt(0)+sched_barrier, vmcnt(0), barrier, MFMA}.
// cvt/gen fusion + XCD chunk swizzle + runtime split merge from R18.

typedef _Float16 half8 __attribute__((ext_vector_type(8)));
typedef float f32x4 __attribute__((ext_vector_type(4)));
typedef unsigned int uint32;

constexpr int TILE_E = 256 * 32;  // 8192 f16 = 16KB

__device__ __forceinline__ unsigned short f2h_bits(float f) {
  _Float16 h = (_Float16)f;
  return __builtin_bit_cast(unsigned short, h);
}
__device__ __forceinline__ uint32 pk2(float a, float b) {
  return f2h_bits(a) | ((uint32)f2h_bits(b) << 16);
}

__device__ __forceinline__ void gload_lds16(const unsigned short* g, unsigned short* l) {
  __builtin_amdgcn_global_load_lds((const __attribute__((address_space(1))) void*)g,
                                   (__attribute__((address_space(3))) void*)l,
                                   16, 0, 0);
}

#define CFENCE asm volatile("" ::: "memory")

// Stored f16 index for logical (tile row r, 16B k-slot byte cb); stored rows
// are 128B (two logical rows); slot' = ((r&1)<<2 | cb>>4) ^ ((r>>1)&7).
// Measured 0 bank conflicts (R2-R18).
__device__ __forceinline__ int swz_idx(int r, int cbyte) {
  int b = (r >> 1) * 128 + ((((r & 1) << 6) | cbyte) ^ (((r >> 1) & 7) << 4));
  return b >> 1;
}

// Stage a 256x32 f16 tile from G (row-major, stride ld); LDS dest LINEAR,
// swizzle realized by inverse-permuting per-lane global source addresses.
__device__ __forceinline__ void stage_tile(const unsigned short* __restrict__ G,
                                           int rowbase, int k0, int ld,
                                           unsigned short* lds, int wave, int lane) {
#pragma unroll
  for (int c = 0; c < 2; ++c) {
    const int p = c * 64 + wave * 8 + (lane >> 3);   // stored 128B row
    const int v = (lane & 7) ^ ((lane >> 3) & 7);    // inverse slot swizzle
    const int r = 2 * p + (v >> 2);                  // logical tile row
    const int kslot = v & 3;
    const unsigned short* src = G + (size_t)(rowbase + r) * ld + (k0 + kslot * 8);
    unsigned short* dst = lds + (c * 64 + wave * 8) * 64;  // wave-uniform
    gload_lds16(src, dst);
  }
}

// ---- convert + FULL 2-level 2D fold (LDS-bounce) + cosine-matrix gen --------
__global__ __launch_bounds__(512) void cvt_fold22(
    const float* __restrict__ x, unsigned short* __restrict__ Xff,
    unsigned short* __restrict__ C4k, unsigned short* __restrict__ C2h,
    unsigned short* __restrict__ C4h) {
  __shared__ float Y[4][2048];  // 32 KB
  const int blk = blockIdx.x;   // 4096 = b*512 + v
  const int b = blk >> 9;
  const int v = blk & 511;
  const int j = threadIdx.x;    // 0..511
  const float* base = x + (size_t)b * 4194304;
  const float* r0 = base + (size_t)v * 2048;
  const float* r1 = base + (size_t)(2047 - v) * 2048;
  const float* r2 = base + (size_t)(1023 - v) * 2048;
  const float* r3 = base + (size_t)(1024 + v) * 2048;

  {
    const int c = 4 * j;
    float4 a = *(const float4*)(r0 + c);
    float4 bb = *(const float4*)(r1 + c);
    float4 cc = *(const float4*)(r2 + c);
    float4 dd = *(const float4*)(r3 + c);
    float4 sp, sm, d0, d1;
    sp.x = (a.x + bb.x) + (cc.x + dd.x); sm.x = (a.x + bb.x) - (cc.x + dd.x);
    sp.y = (a.y + bb.y) + (cc.y + dd.y); sm.y = (a.y + bb.y) - (cc.y + dd.y);
    sp.z = (a.z + bb.z) + (cc.z + dd.z); sm.z = (a.z + bb.z) - (cc.z + dd.z);
    sp.w = (a.w + bb.w) + (cc.w + dd.w); sm.w = (a.w + bb.w) - (cc.w + dd.w);
    d0.x = a.x - bb.x; d1.x = cc.x - dd.x;
    d0.y = a.y - bb.y; d1.y = cc.y - dd.y;
    d0.z = a.z - bb.z; d1.z = cc.z - dd.z;
    d0.w = a.w - bb.w; d1.w = cc.w - dd.w;
    *(float4*)&Y[0][c] = sp;
    *(float4*)&Y[1][c] = sm;
    *(float4*)&Y[2][c] = d0;
    *(float4*)&Y[3][c] = d1;
  }
  __syncthreads();

  unsigned short* orow[4] = {
      Xff + ((size_t)b * 2048 + v) * 2048,
      Xff + ((size_t)b * 2048 + 512 + v) * 2048,
      Xff + ((size_t)b * 2048 + 1024 + v) * 2048,
      Xff + ((size_t)b * 2048 + 2047 - v) * 2048};
  const int c0 = 4 * j;
  int pA, pD, pB, pC, rng;
  if (j < 128) { rng = 0; pA = 4 * j; pD = 2044 - 4 * j; pB = 1020 - 4 * j; pC = 1024 + 4 * j; }
  else if (j < 256) { rng = 1; pA = 4 * j - 512; pD = 2556 - 4 * j; pB = 1532 - 4 * j; pC = 512 + 4 * j; }
  else { rng = 2; pA = 4 * j - 1024; pD = 3068 - 4 * j; pB = 0; pC = 0; }

#pragma unroll
  for (int t = 0; t < 4; ++t) {
    float val[4];
    float4 av = *(const float4*)&Y[t][pA];
    float4 dv = *(const float4*)&Y[t][pD];
    const float* A = (const float*)&av;
    const float* Dq = (const float*)&dv;
    if (rng == 2) {
#pragma unroll
      for (int e = 0; e < 4; ++e) val[e] = A[e] - Dq[3 - e];
    } else {
      float4 bv = *(const float4*)&Y[t][pB];
      float4 cv = *(const float4*)&Y[t][pC];
      const float* Bq = (const float*)&bv;
      const float* Cq = (const float*)&cv;
#pragma unroll
      for (int e = 0; e < 4; ++e) {
        float P = A[e] + Dq[3 - e];
        float M = Bq[3 - e] + Cq[e];
        val[e] = rng == 0 ? P + M : P - M;
      }
    }
    *(uint2*)(orow[t] + c0) = make_uint2(pk2(val[0], val[1]), pk2(val[2], val[3]));
  }

  // gen tail: cosine matrices (each idx exactly once; 2M threads >= 1572864)
  const int idx = blk * 512 + j;
  const float s = 7.6699039394282061e-4f;  // pi/4096
  if (idx < 1048576) {
    int k = idx >> 10, n = idx & 1023;
    int t = ((2 * n + 1) * (2 * k + 1)) & 8191;   // DCT-IV 1024
    C4k[idx] = f2h_bits(cosf((float)t * s));
  } else if (idx < 1310720) {
    int i2 = idx - 1048576;
    int k = i2 >> 9, n = i2 & 511;
    int t = ((2 * n + 1) * 4 * k) & 8191;         // DCT-II 512
    C2h[i2] = f2h_bits(cosf((float)t * s));
  } else if (idx < 1572864) {
    int i2 = idx - 1310720;
    int k = i2 >> 9, n = i2 & 511;
    int t = ((2 * n + 1) * (4 * k + 2)) & 8191;   // DCT-IV 512
    C4h[i2] = f2h_bits(cosf((float)t * s));
  }
}

// ---- merged GEMM: 2-buffer/64KB ring (2 blocks/CU) + XCD chunk swizzle ------
// Decode identical to R18. Sync ledger = R5 (HW-validated).
template <int MODE>
__global__ __launch_bounds__(512) void dct_gemm(
    const unsigned short* __restrict__ C4k, const unsigned short* __restrict__ C2h,
    const unsigned short* __restrict__ C4h, const unsigned short* __restrict__ D,
    void* __restrict__ outp) {
  __shared__ unsigned short As[2 * TILE_E];
  __shared__ unsigned short Bs[2 * TILE_E];

  const int tid = threadIdx.x;
  const int lane = tid & 63;
  const int wave = tid >> 6;
  const int wr = wave >> 2;
  const int wc = wave & 3;

  int lin;
  if (MODE == 0)
    lin = blockIdx.y * 8 + blockIdx.x;                       // (8,64) = 512
  else
    lin = (blockIdx.z * 8 + blockIdx.y) * 8 + blockIdx.x;    // (8,8,8) = 512
  const int f = (lin & 7) * 64 + (lin >> 3);                 // bijective, q=64
  const int split = f & 1;
  const int f2 = f >> 1;
  int bnx, bmx, z;
  if (MODE == 0) { bnx = f2 & 3; bmx = f2 >> 2; z = 0; }
  else { bnx = f2 & 7; bmx = (f2 >> 3) & 3; z = f2 >> 5; }

  const unsigned short* Ag;
  const unsigned short* Bg;
  int lda, ldb, arow, brow, cls, NT;
  if (MODE == 0) {
    if (!split) {
      cls = 0; Ag = D + 1024; lda = 2048; arow = bmx * 256;
      Bg = C4k; ldb = 1024; brow = bnx * 256; NT = 32;
    } else {
      cls = bnx >> 1; Ag = D + cls * 512; lda = 2048; arow = bmx * 256;
      Bg = cls ? C4h : C2h; ldb = 512; brow = (bnx & 1) * 256; NT = 16;
    }
  } else {
    if (!split) {
      cls = 0; Ag = C4k; lda = 1024; arow = bmx * 256;
      Bg = D + (size_t)z * 4194304u + 1024; ldb = 2048; brow = bnx * 256; NT = 32;
    } else {
      cls = bmx >> 1; Ag = cls ? C4h : C2h; lda = 512; arow = (bmx & 1) * 256;
      Bg = D + (size_t)z * 4194304u + cls * 512; ldb = 2048; brow = bnx * 256; NT = 16;
    }
  }

  const int frc = lane & 15;
  const int cb = (lane >> 4) << 4;

  f32x4 acc[8][4] = {};

  stage_tile(Ag, arow, 0, lda, &As[0], wave, lane);
  stage_tile(Bg, brow, 0, ldb, &Bs[0], wave, lane);
  asm volatile("s_waitcnt vmcnt(0)" ::: "memory");
  CFENCE; __builtin_amdgcn_s_barrier(); CFENCE;

  for (int t = 0; t < NT; ++t) {
    const unsigned short* at = &As[(t & 1) * TILE_E];
    const unsigned short* bt = &Bs[(t & 1) * TILE_E];
    half8 af[4], bf[4];

    // phase 1: reads (quadrant mh=0) + stage both next-tile operands
#pragma unroll
    for (int m = 0; m < 4; ++m)
      af[m] = *(const half8*)&at[swz_idx(wr * 128 + m * 16 + frc, cb)];
#pragma unroll
    for (int n = 0; n < 4; ++n)
      bf[n] = *(const half8*)&bt[swz_idx(wc * 64 + n * 16 + frc, cb)];
    if (t + 1 < NT) {
      stage_tile(Ag, arow, (t + 1) * 32, lda, &As[((t + 1) & 1) * TILE_E], wave, lane);
      stage_tile(Bg, brow, (t + 1) * 32, ldb, &Bs[((t + 1) & 1) * TILE_E], wave, lane);
    }
    CFENCE; __builtin_amdgcn_s_barrier(); CFENCE;
    __builtin_amdgcn_s_setprio(1);
#pragma unroll
    for (int m = 0; m < 4; ++m)
#pragma unroll
      for (int n = 0; n < 4; ++n)
        acc[m][n] = __builtin_amdgcn_mfma_f32_16x16x32_f16(af[m], bf[n], acc[m][n], 0, 0, 0);
    __builtin_amdgcn_s_setprio(0);

    // phase 2: reads (quadrant mh=1); release this buffer (lgkm) and next
    // tile's loads (vmcnt) before the barrier.
#pragma unroll
    for (int m = 0; m < 4; ++m)
      af[m] = *(const half8*)&at[swz_idx(wr * 128 + 64 + m * 16 + frc, cb)];
    asm volatile("s_waitcnt lgkmcnt(0)" ::: "memory");
    __builtin_amdgcn_sched_barrier(0);
    if (t + 1 < NT)
      asm volatile("s_waitcnt vmcnt(0)" ::: "memory");
    CFENCE; __builtin_amdgcn_s_barrier(); CFENCE;
    __builtin_amdgcn_s_setprio(1);
#pragma unroll
    for (int m = 0; m < 4; ++m)
#pragma unroll
      for (int n = 0; n < 4; ++n)
        acc[m + 4][n] =
            __builtin_amdgcn_mfma_f32_16x16x32_f16(af[m], bf[n], acc[m + 4][n], 0, 0, 0);
    __builtin_amdgcn_s_setprio(0);
  }

  // epilogue; D mapping: col = lane&15, row = (lane>>4)*4 + i
  if (MODE == 0) {
    unsigned short* U2t = (unsigned short*)outp;
#pragma unroll
    for (int mi = 0; mi < 8; ++mi) {
      const int r = arow + wr * 128 + (mi >> 2) * 64 + (mi & 3) * 16 + (lane >> 4) * 4;
      const int b = r >> 11;
      const int rb = r & 2047;
#pragma unroll
      for (int n = 0; n < 4; ++n) {
        const int ccls = brow + wc * 64 + n * 16 + frc;
        const int ktrue = split ? (4 * ccls + 2 * cls) : (2 * ccls + 1);
        uint32 lo = f2h_bits(acc[mi][n][0]) | ((uint32)f2h_bits(acc[mi][n][1]) << 16);
        uint32 hi = f2h_bits(acc[mi][n][2]) | ((uint32)f2h_bits(acc[mi][n][3]) << 16);
        *(uint2*)&U2t[(size_t)b * 4194304 + (size_t)ktrue * 2048 + rb] =
            make_uint2(lo, hi);
      }
    }
  } else {
    float* out = (float*)outp + (size_t)z * 4194304;
#pragma unroll
    for (int mi = 0; mi < 8; ++mi) {
      const int p0 = arow + wr * 128 + (mi >> 2) * 64 + (mi & 3) * 16 + (lane >> 4) * 4;
#pragma unroll
      for (int n = 0; n < 4; ++n) {
        const int cg = brow + wc * 64 + n * 16 + frc;
#pragma unroll
        for (int i = 0; i < 4; ++i) {
          const int rtrue = split ? (4 * (p0 + i) + 2 * cls) : (2 * (p0 + i) + 1);
          out[(size_t)rtrue * 2048 + cg] = acc[mi][n][i];
        }
      }
    }
  }
}

extern "C" void kernel_launch(void* const* d_in, const int* in_sizes, int n_in,
                              void* d_out, int out_size, void* d_ws,
                              size_t ws_size, hipStream_t stream) {
  const float* x = (const float*)d_in[0];
  float* out = (float*)d_out;

  // workspace (f16 elems):
  // Xff 33554432 | C4k 1048576 | C2h 262144 | C4h 262144 | U2t 33554432
  unsigned short* Xff = (unsigned short*)d_ws;
  unsigned short* C4k = Xff + 33554432u;
  unsigned short* C2h = C4k + 1048576u;
  unsigned short* C4h = C2h + 262144u;
  unsigned short* U2t = C4h + 262144u;

  cvt_fold22<<<4096, 512, 0, stream>>>(x, Xff, C4k, C2h, C4h);
  dct_gemm<0><<<dim3(8, 64, 1), 512, 0, stream>>>(C4k, C2h, C4h, Xff, (void*)U2t);
  dct_gemm<1><<<dim3(8, 8, 8), 512, 0, stream>>>(C4k, C2h, C4h, U2t, (void*)out);
}

// Round 20
// 189.363 us; speedup vs baseline: 1.0386x; 1.0386x over previous
//
#include <hip/hip_runtime.h>
#include <hip/hip_bf16.h>
#include <hip/hip_fp16.h>

// 2D DCT-II via LEVEL-2 folded f16 MFMA GEMMs.  (R20 = R17 verbatim — best
// measured config, 189.386 us. R19's 2-buffer ring regressed: occupancy did
// not rise; R16's 8-phase port raced; this 4-buffer counted-vmcnt structure
// is the verified optimum under this harness.)
// Per 2048-DCT: k odd -> DCT4-1024 on w (K=1024); k=4s -> DCT2-512 on u+
// (K=512); k=4s+2 -> DCT4-512 on u- (K=512). MACs = 0.75x of level-1; both
// dims' 2-level folds fused into cvt_fold22 (f32 in, f16 out, LDS-bounce,
// conflict-free). GEMM: 256x256, 8 waves, BK=32, 4-buffer ring, counted
// vmcnt(4), XOR LDS swizzle (0 conflicts), setprio, bijective XCD chunk
// swizzle.

typedef _Float16 half8 __attribute__((ext_vector_type(8)));
typedef float f32x4 __attribute__((ext_vector_type(4)));
typedef unsigned int uint32;

constexpr int TILE_E = 256 * 32;  // 8192 f16 = 16KB

__device__ __forceinline__ unsigned short f2h_bits(float f) {
  _Float16 h = (_Float16)f;
  return __builtin_bit_cast(unsigned short, h);
}
__device__ __forceinline__ uint32 pk2(float a, float b) {
  return f2h_bits(a) | ((uint32)f2h_bits(b) << 16);
}

__device__ __forceinline__ void gload_lds16(const unsigned short* g, unsigned short* l) {
  __builtin_amdgcn_global_load_lds((const __attribute__((address_space(1))) void*)g,
                                   (__attribute__((address_space(3))) void*)l,
                                   16, 0, 0);
}

#define CFENCE asm volatile("" ::: "memory")

// Stored f16 index for logical (tile row r, 16B k-slot byte cb); stored rows
// are 128B (two logical rows); slot' = ((r&1)<<2 | cb>>4) ^ ((r>>1)&7).
// Measured 0 bank conflicts (R2-R19).
__device__ __forceinline__ int swz_idx(int r, int cbyte) {
  int b = (r >> 1) * 128 + ((((r & 1) << 6) | cbyte) ^ (((r >> 1) & 7) << 4));
  return b >> 1;
}

// Stage a 256x32 f16 tile from G (row-major, stride ld); LDS dest LINEAR,
// swizzle realized by inverse-permuting per-lane global source addresses.
__device__ __forceinline__ void stage_tile(const unsigned short* __restrict__ G,
                                           int rowbase, int k0, int ld,
                                           unsigned short* lds, int wave, int lane) {
#pragma unroll
  for (int c = 0; c < 2; ++c) {
    const int p = c * 64 + wave * 8 + (lane >> 3);   // stored 128B row
    const int v = (lane & 7) ^ ((lane >> 3) & 7);    // inverse slot swizzle
    const int r = 2 * p + (v >> 2);                  // logical tile row
    const int kslot = v & 3;
    const unsigned short* src = G + (size_t)(rowbase + r) * ld + (k0 + kslot * 8);
    unsigned short* dst = lds + (c * 64 + wave * 8) * 64;  // wave-uniform
    gload_lds16(src, dst);
  }
}

// ---- convert + FULL 2-level 2D fold, LDS-bounce, conflict-free --------------
__global__ __launch_bounds__(512) void cvt_fold22(const float* __restrict__ x,
                                                  unsigned short* __restrict__ Xff) {
  __shared__ float Y[4][2048];  // 32 KB
  const int blk = blockIdx.x;   // 4096 = b*512 + v
  const int b = blk >> 9;
  const int v = blk & 511;
  const int j = threadIdx.x;    // 0..511
  const float* base = x + (size_t)b * 4194304;
  const float* r0 = base + (size_t)v * 2048;
  const float* r1 = base + (size_t)(2047 - v) * 2048;
  const float* r2 = base + (size_t)(1023 - v) * 2048;
  const float* r3 = base + (size_t)(1024 + v) * 2048;

  // phase 1: one float4 col-chunk per thread per row (c = 4j)
  {
    const int c = 4 * j;
    float4 a = *(const float4*)(r0 + c);
    float4 bb = *(const float4*)(r1 + c);
    float4 cc = *(const float4*)(r2 + c);
    float4 dd = *(const float4*)(r3 + c);
    float4 sp, sm, d0, d1;
    sp.x = (a.x + bb.x) + (cc.x + dd.x); sm.x = (a.x + bb.x) - (cc.x + dd.x);
    sp.y = (a.y + bb.y) + (cc.y + dd.y); sm.y = (a.y + bb.y) - (cc.y + dd.y);
    sp.z = (a.z + bb.z) + (cc.z + dd.z); sm.z = (a.z + bb.z) - (cc.z + dd.z);
    sp.w = (a.w + bb.w) + (cc.w + dd.w); sm.w = (a.w + bb.w) - (cc.w + dd.w);
    d0.x = a.x - bb.x; d1.x = cc.x - dd.x;
    d0.y = a.y - bb.y; d1.y = cc.y - dd.y;
    d0.z = a.z - bb.z; d1.z = cc.z - dd.z;
    d0.w = a.w - bb.w; d1.w = cc.w - dd.w;
    *(float4*)&Y[0][c] = sp;
    *(float4*)&Y[1][c] = sm;
    *(float4*)&Y[2][c] = d0;
    *(float4*)&Y[3][c] = d1;
  }
  __syncthreads();

  // phase 2: thread j -> output cols [4j, 4j+4) for all 4 output rows
  unsigned short* orow[4] = {
      Xff + ((size_t)b * 2048 + v) * 2048,
      Xff + ((size_t)b * 2048 + 512 + v) * 2048,
      Xff + ((size_t)b * 2048 + 1024 + v) * 2048,
      Xff + ((size_t)b * 2048 + 2047 - v) * 2048};
  const int c0 = 4 * j;
  int pA, pD, pB, pC, rng;
  if (j < 128) { rng = 0; pA = 4 * j; pD = 2044 - 4 * j; pB = 1020 - 4 * j; pC = 1024 + 4 * j; }
  else if (j < 256) { rng = 1; pA = 4 * j - 512; pD = 2556 - 4 * j; pB = 1532 - 4 * j; pC = 512 + 4 * j; }
  else { rng = 2; pA = 4 * j - 1024; pD = 3068 - 4 * j; pB = 0; pC = 0; }

#pragma unroll
  for (int t = 0; t < 4; ++t) {
    float val[4];
    float4 av = *(const float4*)&Y[t][pA];
    float4 dv = *(const float4*)&Y[t][pD];
    const float* A = (const float*)&av;
    const float* Dq = (const float*)&dv;
    if (rng == 2) {
#pragma unroll
      for (int e = 0; e < 4; ++e) val[e] = A[e] - Dq[3 - e];
    } else {
      float4 bv = *(const float4*)&Y[t][pB];
      float4 cv = *(const float4*)&Y[t][pC];
      const float* Bq = (const float*)&bv;
      const float* Cq = (const float*)&cv;
#pragma unroll
      for (int e = 0; e < 4; ++e) {
        float P = A[e] + Dq[3 - e];
        float M = Bq[3 - e] + Cq[e];
        val[e] = rng == 0 ? P + M : P - M;
      }
    }
    *(uint2*)(orow[t] + c0) = make_uint2(pk2(val[0], val[1]), pk2(val[2], val[3]));
  }
}

// ---- cosine matrices: C4k 1024x1024 (DCT-IV), C2h 512x512, C4h 512x512 ------
__global__ __launch_bounds__(256) void gen_cos3(unsigned short* __restrict__ C4k,
                                                unsigned short* __restrict__ C2h,
                                                unsigned short* __restrict__ C4h) {
  int idx = blockIdx.x * 256 + threadIdx.x;  // 1572864
  const float s = 7.6699039394282061e-4f;    // pi/4096
  if (idx < 1048576) {
    int k = idx >> 10, n = idx & 1023;
    int t = ((2 * n + 1) * (2 * k + 1)) & 8191;   // cos(pi(2n+1)(2k+1)/4096)
    C4k[idx] = f2h_bits(cosf((float)t * s));
  } else if (idx < 1310720) {
    int i2 = idx - 1048576;
    int k = i2 >> 9, n = i2 & 511;
    int t = ((2 * n + 1) * 4 * k) & 8191;         // cos(pi(2n+1)k/1024)
    C2h[i2] = f2h_bits(cosf((float)t * s));
  } else {
    int i2 = idx - 1310720;
    int k = i2 >> 9, n = i2 & 511;
    int t = ((2 * n + 1) * (4 * k + 2)) & 8191;   // cos(pi(2n+1)(2k+1)/2048)
    C4h[i2] = f2h_bits(cosf((float)t * s));
  }
}

// ---- pipelined GEMM (R11 structure) + bijective XCD chunk swizzle -----------
// MODE 0 (stage 1, f16 transposed out U2t[b][ktrue][m2]):
//   SPLIT 0: A cols [1024,2048)=w, B=M0=C4k,  K=1024, ktrue=2c+1
//   SPLIT 1: cls=bn>>1: A cols cls*512 (u+/u-), B=C2h/C4h, K=512, ktrue=4c+2cls
// MODE 1 (stage 2, fp32 out):
//   SPLIT 0: A=C4k (M=1024), B=U2t[z] cols [1024,2048), K=1024, rtrue=2p+1
//   SPLIT 1: cls=by>>1: A=C2h/C4h, B=U2t[z] cols cls*512, K=512, rtrue=4p+2cls
template <int MODE, int SPLIT>
__global__ __launch_bounds__(512) void dct_gemm(
    const unsigned short* __restrict__ M0, const unsigned short* __restrict__ M1,
    const unsigned short* __restrict__ D, void* __restrict__ outp) {
  constexpr int K = SPLIT ? 512 : 1024;
  constexpr int NT = K / 32;
  __shared__ unsigned short As[4 * TILE_E];
  __shared__ unsigned short Bs[4 * TILE_E];

  const int tid = threadIdx.x;
  const int lane = tid & 63;
  const int wave = tid >> 6;
  const int wr = wave >> 2;
  const int wc = wave & 3;

  // XCD-chunked bijective remap (nwg = 256 for all instantiations)
  int lin, f, bmx, bnx, z;
  if (MODE == 0) {
    lin = blockIdx.y * 4 + blockIdx.x;            // gx=4, gy=64
    f = (lin & 7) * 32 + (lin >> 3);
    bnx = f & 3;
    bmx = f >> 2;
    z = 0;
  } else {
    lin = (blockIdx.z * 4 + blockIdx.y) * 8 + blockIdx.x;  // gx=8, gy=4, gz=8
    f = (lin & 7) * 32 + (lin >> 3);
    bnx = f & 7;
    bmx = (f >> 3) & 3;
    z = f >> 5;
  }

  const unsigned short* Ag;
  const unsigned short* Bg;
  int lda, ldb, arow, brow, cls;
  if (MODE == 0) {
    cls = SPLIT ? (bnx >> 1) : 0;
    Ag = D + (SPLIT ? cls * 512 : 1024);
    lda = 2048;
    arow = bmx * 256;
    Bg = SPLIT ? (cls ? M1 : M0) : M0;
    ldb = K;
    brow = (SPLIT ? (bnx & 1) : bnx) * 256;
  } else {
    cls = SPLIT ? (bmx >> 1) : 0;
    Ag = SPLIT ? (cls ? M1 : M0) : M0;
    lda = K;
    arow = (SPLIT ? (bmx & 1) : bmx) * 256;
    Bg = D + (size_t)z * 4194304u + (SPLIT ? cls * 512 : 1024);
    ldb = 2048;
    brow = bnx * 256;
  }

  const int frc = lane & 15;
  const int cb = (lane >> 4) << 4;

  f32x4 acc[8][4] = {};

  stage_tile(Ag, arow, 0, lda, &As[0], wave, lane);
  stage_tile(Bg, brow, 0, ldb, &Bs[0], wave, lane);
  stage_tile(Ag, arow, 32, lda, &As[TILE_E], wave, lane);
  stage_tile(Bg, brow, 32, ldb, &Bs[TILE_E], wave, lane);
  asm volatile("s_waitcnt vmcnt(4)" ::: "memory");
  CFENCE; __builtin_amdgcn_s_barrier(); CFENCE;

  for (int t = 0; t < NT; ++t) {
    const unsigned short* at = &As[(t & 3) * TILE_E];
    const unsigned short* bt = &Bs[(t & 3) * TILE_E];
    half8 af[4], bf[4];

    // phase 1: reads (quadrant mh=0) + stage A(t+2)
#pragma unroll
    for (int m = 0; m < 4; ++m)
      af[m] = *(const half8*)&at[swz_idx(wr * 128 + m * 16 + frc, cb)];
#pragma unroll
    for (int n = 0; n < 4; ++n)
      bf[n] = *(const half8*)&bt[swz_idx(wc * 64 + n * 16 + frc, cb)];
    if (t + 2 < NT)
      stage_tile(Ag, arow, (t + 2) * 32, lda, &As[((t + 2) & 3) * TILE_E], wave, lane);
    CFENCE; __builtin_amdgcn_s_barrier(); CFENCE;
    __builtin_amdgcn_s_setprio(1);
#pragma unroll
    for (int m = 0; m < 4; ++m)
#pragma unroll
      for (int n = 0; n < 4; ++n)
        acc[m][n] = __builtin_amdgcn_mfma_f32_16x16x32_f16(af[m], bf[n], acc[m][n], 0, 0, 0);
    __builtin_amdgcn_s_setprio(0);

    // phase 2: reads (quadrant mh=1) + stage B(t+2) + counted boundary
#pragma unroll
    for (int m = 0; m < 4; ++m)
      af[m] = *(const half8*)&at[swz_idx(wr * 128 + 64 + m * 16 + frc, cb)];
    if (t + 2 < NT)
      stage_tile(Bg, brow, (t + 2) * 32, ldb, &Bs[((t + 2) & 3) * TILE_E], wave, lane);
    if (t < NT - 2)
      asm volatile("s_waitcnt vmcnt(4)" ::: "memory");
    else if (t == NT - 2)
      asm volatile("s_waitcnt vmcnt(0)" ::: "memory");
    CFENCE; __builtin_amdgcn_s_barrier(); CFENCE;
    __builtin_amdgcn_s_setprio(1);
#pragma unroll
    for (int m = 0; m < 4; ++m)
#pragma unroll
      for (int n = 0; n < 4; ++n)
        acc[m + 4][n] =
            __builtin_amdgcn_mfma_f32_16x16x32_f16(af[m], bf[n], acc[m + 4][n], 0, 0, 0);
    __builtin_amdgcn_s_setprio(0);
  }

  // epilogue; D mapping: col = lane&15, row = (lane>>4)*4 + i
  if (MODE == 0) {
    unsigned short* U2t = (unsigned short*)outp;
#pragma unroll
    for (int mi = 0; mi < 8; ++mi) {
      const int r = arow + wr * 128 + (mi >> 2) * 64 + (mi & 3) * 16 + (lane >> 4) * 4;
      const int b = r >> 11;
      const int rb = r & 2047;
#pragma unroll
      for (int n = 0; n < 4; ++n) {
        const int ccls = brow + wc * 64 + n * 16 + frc;
        const int ktrue = SPLIT ? (4 * ccls + 2 * cls) : (2 * ccls + 1);
        uint32 lo = f2h_bits(acc[mi][n][0]) | ((uint32)f2h_bits(acc[mi][n][1]) << 16);
        uint32 hi = f2h_bits(acc[mi][n][2]) | ((uint32)f2h_bits(acc[mi][n][3]) << 16);
        *(uint2*)&U2t[(size_t)b * 4194304 + (size_t)ktrue * 2048 + rb] =
            make_uint2(lo, hi);
      }
    }
  } else {
    float* out = (float*)outp + (size_t)z * 4194304;
#pragma unroll
    for (int mi = 0; mi < 8; ++mi) {
      const int p0 = arow + wr * 128 + (mi >> 2) * 64 + (mi & 3) * 16 + (lane >> 4) * 4;
#pragma unroll
      for (int n = 0; n < 4; ++n) {
        const int cg = brow + wc * 64 + n * 16 + frc;
#pragma unroll
        for (int i = 0; i < 4; ++i) {
          const int rtrue = SPLIT ? (4 * (p0 + i) + 2 * cls) : (2 * (p0 + i) + 1);
          out[(size_t)rtrue * 2048 + cg] = acc[mi][n][i];
        }
      }
    }
  }
}

extern "C" void kernel_launch(void* const* d_in, const int* in_sizes, int n_in,
                              void* d_out, int out_size, void* d_ws,
                              size_t ws_size, hipStream_t stream) {
  const float* x = (const float*)d_in[0];
  float* out = (float*)d_out;

  // workspace (f16 elems):
  // Xff 33554432 | C4k 1048576 | C2h 262144 | C4h 262144 | U2t 33554432
  unsigned short* Xff = (unsigned short*)d_ws;
  unsigned short* C4k = Xff + 33554432u;
  unsigned short* C2h = C4k + 1048576u;
  unsigned short* C4h = C2h + 262144u;
  unsigned short* U2t = C4h + 262144u;

  cvt_fold22<<<4096, 512, 0, stream>>>(x, Xff);  // one block per (b,v): 8*512
  gen_cos3<<<6144, 256, 0, stream>>>(C4k, C2h, C4h);
  // stage 1: odd k (K=1024) and even k (K=512, u+/u- classes)
  dct_gemm<0, 0><<<dim3(4, 64, 1), 512, 0, stream>>>(C4k, C4k, Xff, (void*)U2t);
  dct_gemm<0, 1><<<dim3(4, 64, 1), 512, 0, stream>>>(C2h, C4h, Xff, (void*)U2t);
  // stage 2: odd rows (K=1024) and even rows (K=512)
  dct_gemm<1, 0><<<dim3(8, 4, 8), 512, 0, stream>>>(C4k, C4k, U2t, (void*)out);
  dct_gemm<1, 1><<<dim3(8, 4, 8), 512, 0, stream>>>(C2h, C4h, U2t, (void*)out);
}